// Round 2
// baseline (1032.756 us; speedup 1.0000x reference)
//
#include <hip/hip_runtime.h>
#include <math.h>

#define NTOK 16384
#define DIM 2048
#define NEXP 64
#define BT 64              // tokens per block
#define KC 32              // k per stage
#define NSTAGE (DIM / KC)  // 64
#define PITCH (BT + 1)     // 65: conflict-free column reads

// flat output offsets (return order)
#define OFF_W    0
#define OFF_I    32768
#define OFF_P    65536
#define OFF_ENT  1114112
#define OFF_CONF 1114113
#define OFF_UTIL 1114114

__global__ void router_init(float* __restrict__ out) {
    int tid = threadIdx.x;
    if (tid < 66) out[OFF_ENT + tid] = 0.0f;
}

__global__ __launch_bounds__(256) void router_main(
    const float* __restrict__ x, const float* __restrict__ Wg,
    float* __restrict__ out)
{
    // xs: [k][token] transposed, double-buffered
    __shared__ float xs[2][KC][PITCH];
    // logits [token][expert] pitch 65
    __shared__ float lg[BT][NEXP + 1];
    __shared__ float m1s[BT], rss[BT];
    __shared__ float s_ent, s_conf, s_cnt[NEXP];

    const int tid  = threadIdx.x;
    const int lane = tid & 63;                                // token within block
    const int wv   = __builtin_amdgcn_readfirstlane(tid >> 6); // wave id 0..3 (SGPR!)
    const int ew0  = wv * 16;                                  // this wave's expert base
    const int t0   = blockIdx.x * BT;

    if (tid == 0) { s_ent = 0.0f; s_conf = 0.0f; }
    if (tid < NEXP) s_cnt[tid] = 0.0f;

    // staging: thread (tk = tid>>3 in 0..31, q = tid&7) loads rows tk and tk+32
    const int tk = tid >> 3;
    const int q  = tid & 7;
    const float* xg0 = x + (size_t)(t0 + tk) * DIM + 4 * q;
    const float* xg1 = xg0 + (size_t)32 * DIM;

    // prologue: stage 0
    float4 xa = *(const float4*)xg0;
    float4 xb = *(const float4*)xg1;
    xs[0][4*q+0][tk]    = xa.x; xs[0][4*q+1][tk]    = xa.y;
    xs[0][4*q+2][tk]    = xa.z; xs[0][4*q+3][tk]    = xa.w;
    xs[0][4*q+0][tk+32] = xb.x; xs[0][4*q+1][tk+32] = xb.y;
    xs[0][4*q+2][tk+32] = xb.z; xs[0][4*q+3][tk+32] = xb.w;
    __syncthreads();

    float acc[16];
    #pragma unroll
    for (int e = 0; e < 16; ++e) acc[e] = 0.0f;

    for (int s = 0; s < NSTAGE; ++s) {
        const int b = s & 1;
        if (s + 1 < NSTAGE) {
            const int kn = (s + 1) * KC;
            xa = *(const float4*)(xg0 + kn);
            xb = *(const float4*)(xg1 + kn);
        }

        // this lane's x column for the stage: 32 regs, conflict-free ds_reads
        float xv[KC];
        #pragma unroll
        for (int k = 0; k < KC; ++k) xv[k] = xs[b][k][lane];

        // W is wave-uniform (SGPR base + uniform offsets) -> scalar loads,
        // FMA consumes W as the scalar operand. Zero LDS, zero VALU for W.
        const float* wrow = Wg + (size_t)ew0 * DIM + s * KC;
        #pragma unroll
        for (int e = 0; e < 16; ++e) {
            const float* wp = wrow + (size_t)e * DIM;
            #pragma unroll
            for (int k4 = 0; k4 < KC; k4 += 4) {
                float4 wf = *(const float4*)(wp + k4);
                acc[e] = fmaf(xv[k4+0], wf.x, acc[e]);
                acc[e] = fmaf(xv[k4+1], wf.y, acc[e]);
                acc[e] = fmaf(xv[k4+2], wf.z, acc[e]);
                acc[e] = fmaf(xv[k4+3], wf.w, acc[e]);
            }
        }

        if (s + 1 < NSTAGE) {
            const int nb = b ^ 1;
            xs[nb][4*q+0][tk]    = xa.x; xs[nb][4*q+1][tk]    = xa.y;
            xs[nb][4*q+2][tk]    = xa.z; xs[nb][4*q+3][tk]    = xa.w;
            xs[nb][4*q+0][tk+32] = xb.x; xs[nb][4*q+1][tk+32] = xb.y;
            xs[nb][4*q+2][tk+32] = xb.z; xs[nb][4*q+3][tk+32] = xb.w;
        }
        __syncthreads();
    }

    // scatter logits to LDS: lane t writes its 16-expert strip (conflict-free)
    #pragma unroll
    for (int e = 0; e < 16; ++e)
        lg[lane][ew0 + e] = acc[e];
    __syncthreads();

    // one wave: top-2 + softmax stats per token
    if (tid < BT) {
        const int t = tid;
        float m1 = -INFINITY, m2 = -INFINITY;
        int i1 = 0, i2 = 0;
        for (int e = 0; e < NEXP; ++e) {
            float l = lg[t][e];
            if (l > m1)      { m2 = m1; i2 = i1; m1 = l; i1 = e; }
            else if (l > m2) { m2 = l; i2 = e; }
        }
        float ssum = 0.0f, tsum = 0.0f;
        for (int e = 0; e < NEXP; ++e) {
            float d = lg[t][e] - m1;
            float ex = __expf(d);
            ssum += ex;
            tsum += d * ex;
        }
        float rs = 1.0f / ssum;
        // H = ln(s) - (sum d e^d)/s
        float H  = logf(ssum) - tsum * rs;
        float e2 = __expf(m2 - m1);
        float rn = 1.0f / (1.0f + e2);
        float w0 = rn, w1v = e2 * rn;
        m1s[t] = m1; rss[t] = rs;

        *(float2*)&out[OFF_W + 2*(t0 + t)] = make_float2(w0, w1v);
        *(float2*)&out[OFF_I + 2*(t0 + t)] = make_float2((float)i1, (float)i2);

        atomicAdd(&s_ent,  H);
        atomicAdd(&s_conf, w0);
        atomicAdd(&s_cnt[i1], 1.0f);
        atomicAdd(&s_cnt[i2], 1.0f);
    }
    __syncthreads();

    // cooperative, coalesced probs write: 1024 float4s / 256 threads
    #pragma unroll
    for (int p = 0; p < 4; ++p) {
        int Q  = tid + 256 * p;
        int t  = Q >> 4;
        int qq = Q & 15;
        float m  = m1s[t];
        float rs = rss[t];
        float4 pr;
        pr.x = __expf(lg[t][4*qq + 0] - m) * rs;
        pr.y = __expf(lg[t][4*qq + 1] - m) * rs;
        pr.z = __expf(lg[t][4*qq + 2] - m) * rs;
        pr.w = __expf(lg[t][4*qq + 3] - m) * rs;
        *(float4*)&out[OFF_P + (size_t)(t0 + t) * NEXP + 4*qq] = pr;
    }

    // stats: pre-scaled so the atomic sums are exact / final means
    if (tid == 0) {
        atomicAdd(&out[OFF_ENT],  s_ent  * (1.0f / 16384.0f));
        atomicAdd(&out[OFF_CONF], s_conf * (1.0f / 16384.0f));
    }
    if (tid < NEXP)
        atomicAdd(&out[OFF_UTIL + tid], s_cnt[tid] * (1.0f / 32768.0f));
}

extern "C" void kernel_launch(void* const* d_in, const int* in_sizes, int n_in,
                              void* d_out, int out_size, void* d_ws, size_t ws_size,
                              hipStream_t stream) {
    const float* x  = (const float*)d_in[0];
    const float* Wg = (const float*)d_in[1];
    float* out = (float*)d_out;
    (void)d_ws; (void)ws_size; (void)in_sizes; (void)n_in; (void)out_size;

    router_init<<<dim3(1), dim3(128), 0, stream>>>(out);
    router_main<<<dim3(NTOK / BT), dim3(256), 0, stream>>>(x, Wg, out);
}

// Round 3
// 809.859 us; speedup vs baseline: 1.2752x; 1.2752x over previous
//
#include <hip/hip_runtime.h>
#include <math.h>

#define NTOK 16384
#define DIM 2048
#define NEXP 64
#define BT 64              // tokens per block (= wave size; all 4 waves share them)
#define KC 32              // k per stage
#define NSTAGE (DIM / KC)  // 64

// flat output offsets (return order)
#define OFF_W    0
#define OFF_I    32768
#define OFF_P    65536
#define OFF_ENT  1114112
#define OFF_CONF 1114113
#define OFF_UTIL 1114114

__global__ void router_init(float* __restrict__ out) {
    int tid = threadIdx.x;
    if (tid < 66) out[OFF_ENT + tid] = 0.0f;
}

// Load 32 k-values (8 float4) of this lane's token row for stage s_.
#define LOADX(buf_, s_)                                                  \
    {                                                                    \
        _Pragma("unroll")                                                \
        for (int i = 0; i < 8; ++i)                                      \
            buf_[i] = *(const float4*)(xrow + (s_) * KC + 4 * i);        \
    }

// 16 experts x 32 k FMA nest; W address is wave-uniform -> s_load path.
#define COMPUTE(buf_, s_)                                                \
    {                                                                    \
        const float* wp = wbase + (s_) * KC;                             \
        _Pragma("unroll")                                                \
        for (int e = 0; e < 16; ++e) {                                   \
            const float* w = wp + (size_t)e * DIM;                       \
            _Pragma("unroll")                                            \
            for (int i = 0; i < 8; ++i) {                                \
                float4 wf = *(const float4*)(w + 4 * i);                 \
                acc[e] = fmaf(buf_[i].x, wf.x, acc[e]);                  \
                acc[e] = fmaf(buf_[i].y, wf.y, acc[e]);                  \
                acc[e] = fmaf(buf_[i].z, wf.z, acc[e]);                  \
                acc[e] = fmaf(buf_[i].w, wf.w, acc[e]);                  \
            }                                                            \
        }                                                                \
    }

__global__ __launch_bounds__(256) void router_main(
    const float* __restrict__ x, const float* __restrict__ Wg,
    float* __restrict__ out)
{
    // LDS only for the epilogue
    __shared__ float lg[BT][NEXP + 1];   // pitch 65: 2-way bank alias = free
    __shared__ float m1s[BT], rss[BT];
    __shared__ float s_ent, s_conf, s_cnt[NEXP];

    const int tid  = threadIdx.x;
    const int lane = tid & 63;                                 // token within block
    const int wv   = __builtin_amdgcn_readfirstlane(tid >> 6); // wave id (SGPR)
    const int ew0  = wv * 16;                                  // wave's expert base
    const int t0   = blockIdx.x * BT;

    if (tid == 0) { s_ent = 0.0f; s_conf = 0.0f; }
    if (tid < NEXP) s_cnt[tid] = 0.0f;

    const float* xrow  = x  + (size_t)(t0 + lane) * DIM;  // per-lane token row
    const float* wbase = Wg + (size_t)ew0 * DIM;          // wave-uniform

    float acc[16];
    #pragma unroll
    for (int e = 0; e < 16; ++e) acc[e] = 0.0f;

    float4 xa[8], xb[8];
    LOADX(xa, 0);
    for (int s = 0; s < NSTAGE; s += 2) {
        LOADX(xb, s + 1);                      // s+1 <= 63, always in-bounds
        COMPUTE(xa, s);
        if (s + 2 < NSTAGE) LOADX(xa, s + 2);
        COMPUTE(xb, s + 1);
    }

    // scatter logits: lane t writes its wave's 16-expert strip
    #pragma unroll
    for (int e = 0; e < 16; ++e)
        lg[lane][ew0 + e] = acc[e];
    __syncthreads();

    // one wave: top-2 + softmax stats per token
    if (tid < BT) {
        const int t = tid;
        float m1 = -INFINITY, m2 = -INFINITY;
        int i1 = 0, i2 = 0;
        for (int e = 0; e < NEXP; ++e) {
            float l = lg[t][e];
            if (l > m1)      { m2 = m1; i2 = i1; m1 = l; i1 = e; }
            else if (l > m2) { m2 = l; i2 = e; }
        }
        float ssum = 0.0f, tsum = 0.0f;
        for (int e = 0; e < NEXP; ++e) {
            float d = lg[t][e] - m1;
            float ex = __expf(d);
            ssum += ex;
            tsum += d * ex;
        }
        float rs = 1.0f / ssum;
        // H = ln(s) - (sum d e^d)/s
        float H  = logf(ssum) - tsum * rs;
        float e2 = __expf(m2 - m1);
        float rn = 1.0f / (1.0f + e2);
        float w0 = rn, w1v = e2 * rn;
        m1s[t] = m1; rss[t] = rs;

        *(float2*)&out[OFF_W + 2*(t0 + t)] = make_float2(w0, w1v);
        *(float2*)&out[OFF_I + 2*(t0 + t)] = make_float2((float)i1, (float)i2);

        atomicAdd(&s_ent,  H);
        atomicAdd(&s_conf, w0);
        atomicAdd(&s_cnt[i1], 1.0f);
        atomicAdd(&s_cnt[i2], 1.0f);
    }
    __syncthreads();

    // cooperative, coalesced probs write: 1024 float4s / 256 threads
    #pragma unroll
    for (int p = 0; p < 4; ++p) {
        int Q  = tid + 256 * p;
        int t  = Q >> 4;
        int qq = Q & 15;
        float m  = m1s[t];
        float rs = rss[t];
        float4 pr;
        pr.x = __expf(lg[t][4*qq + 0] - m) * rs;
        pr.y = __expf(lg[t][4*qq + 1] - m) * rs;
        pr.z = __expf(lg[t][4*qq + 2] - m) * rs;
        pr.w = __expf(lg[t][4*qq + 3] - m) * rs;
        *(float4*)&out[OFF_P + (size_t)(t0 + t) * NEXP + 4*qq] = pr;
    }

    // stats: pre-scaled so the atomic sums are exact / final means
    if (tid == 0) {
        atomicAdd(&out[OFF_ENT],  s_ent  * (1.0f / 16384.0f));
        atomicAdd(&out[OFF_CONF], s_conf * (1.0f / 16384.0f));
    }
    if (tid < NEXP)
        atomicAdd(&out[OFF_UTIL + tid], s_cnt[tid] * (1.0f / 32768.0f));
}

extern "C" void kernel_launch(void* const* d_in, const int* in_sizes, int n_in,
                              void* d_out, int out_size, void* d_ws, size_t ws_size,
                              hipStream_t stream) {
    const float* x  = (const float*)d_in[0];
    const float* Wg = (const float*)d_in[1];
    float* out = (float*)d_out;
    (void)d_ws; (void)ws_size; (void)in_sizes; (void)n_in; (void)out_size;

    router_init<<<dim3(1), dim3(128), 0, stream>>>(out);
    router_main<<<dim3(NTOK / BT), dim3(256), 0, stream>>>(x, Wg, out);
}

// Round 4
// 273.900 us; speedup vs baseline: 3.7706x; 2.9568x over previous
//
#include <hip/hip_runtime.h>
#include <math.h>

#define NTOK 16384
#define DIM 2048
#define NEXP 64
#define BT 64              // tokens per block (4 waves x 16-token MFMA tiles)
#define KC 32              // k per chunk = one MFMA K
#define NSTAGE (DIM / KC)  // 64

// flat output offsets (return order)
#define OFF_W    0
#define OFF_I    32768
#define OFF_P    65536
#define OFF_ENT  1114112
#define OFF_CONF 1114113
#define OFF_UTIL 1114114

typedef short s16x8 __attribute__((ext_vector_type(8)));
typedef float f32x4 __attribute__((ext_vector_type(4)));

__device__ __forceinline__ unsigned short f2bf(float v) {
    unsigned u = __builtin_bit_cast(unsigned, v);
    u = u + 0x7FFFu + ((u >> 16) & 1u);          // RNE
    return (unsigned short)(u >> 16);
}
__device__ __forceinline__ float bf2f(unsigned short b) {
    return __builtin_bit_cast(float, (unsigned)b << 16);
}

__global__ void router_init(float* __restrict__ out) {
    int tid = threadIdx.x;
    if (tid < 66) out[OFF_ENT + tid] = 0.0f;
}

// Split W into 3 bf16 planes (hi/mid/lo), stored fragment-linear:
// plane p, chunk c, ntile nt, lane l -> uint4 at wsp[p*16384 + c*256 + nt*64 + l]
// fragment element j: W[16nt + (l&15)][32c + 8*(l>>4) + j]
__global__ void router_wsplit(const float* __restrict__ Wg, uint4* __restrict__ wsp) {
    const int c = blockIdx.x;
    const int t = threadIdx.x;
    const int nt = t >> 6, l = t & 63;
    const int e  = 16 * nt + (l & 15);
    const int k0 = 32 * c + 8 * (l >> 4);
    const float* src = Wg + (size_t)e * DIM + k0;
    float4 a = *(const float4*)src;
    float4 b = *(const float4*)(src + 4);
    float v[8] = {a.x, a.y, a.z, a.w, b.x, b.y, b.z, b.w};
    unsigned short H[8], M[8], L[8];
    #pragma unroll
    for (int j = 0; j < 8; ++j) {
        H[j] = f2bf(v[j]);  float r = v[j] - bf2f(H[j]);
        M[j] = f2bf(r);     r = r - bf2f(M[j]);
        L[j] = f2bf(r);
    }
    uint4 ph, pm, pl;
    ph.x = H[0] | ((unsigned)H[1] << 16); ph.y = H[2] | ((unsigned)H[3] << 16);
    ph.z = H[4] | ((unsigned)H[5] << 16); ph.w = H[6] | ((unsigned)H[7] << 16);
    pm.x = M[0] | ((unsigned)M[1] << 16); pm.y = M[2] | ((unsigned)M[3] << 16);
    pm.z = M[4] | ((unsigned)M[5] << 16); pm.w = M[6] | ((unsigned)M[7] << 16);
    pl.x = L[0] | ((unsigned)L[1] << 16); pl.y = L[2] | ((unsigned)L[3] << 16);
    pl.z = L[4] | ((unsigned)L[5] << 16); pl.w = L[6] | ((unsigned)L[7] << 16);
    const int idx = c * 256 + t;
    wsp[idx]             = ph;
    wsp[16384 + idx]     = pm;
    wsp[32768 + idx]     = pl;
}

#define LOADX(p_, c_) { xset##p_[0] = xq[8*(c_) + 2*qd]; xset##p_[1] = xq[8*(c_) + 2*qd + 1]; }
#define LOADW(p_, c_) { wset##p_[0] = wq[(c_)*256 + tid];          \
                        wset##p_[1] = wq[16384 + (c_)*256 + tid];  \
                        wset##p_[2] = wq[32768 + (c_)*256 + tid]; }
#define STOREW(p_, bf_) { *(uint4*)&Bs[0][bf_][wv][l8] = wset##p_[0];  \
                          *(uint4*)&Bs[1][bf_][wv][l8] = wset##p_[1];  \
                          *(uint4*)&Bs[2][bf_][wv][l8] = wset##p_[2]; }
#define CONVX(p_) {                                                     \
    float xv[8];                                                        \
    xv[0]=xset##p_[0].x; xv[1]=xset##p_[0].y; xv[2]=xset##p_[0].z; xv[3]=xset##p_[0].w; \
    xv[4]=xset##p_[1].x; xv[5]=xset##p_[1].y; xv[6]=xset##p_[1].z; xv[7]=xset##p_[1].w; \
    _Pragma("unroll")                                                   \
    for (int j = 0; j < 8; ++j) {                                       \
        unsigned short h_ = f2bf(xv[j]); float r_ = xv[j] - bf2f(h_);   \
        unsigned short m_ = f2bf(r_);    r_ = r_ - bf2f(m_);            \
        unsigned short s_ = f2bf(r_);                                   \
        ah[j] = (short)h_; am[j] = (short)m_; al[j] = (short)s_;        \
    } }
#define COMPUTE(bf_) {                                                  \
    _Pragma("unroll")                                                   \
    for (int nt = 0; nt < 4; ++nt) {                                    \
        s16x8 bh_ = *(const s16x8*)&Bs[0][bf_][nt][l8];                 \
        s16x8 bm_ = *(const s16x8*)&Bs[1][bf_][nt][l8];                 \
        s16x8 bl_ = *(const s16x8*)&Bs[2][bf_][nt][l8];                 \
        acc[nt] = __builtin_amdgcn_mfma_f32_16x16x32_bf16(ah, bh_, acc[nt], 0, 0, 0); \
        acc[nt] = __builtin_amdgcn_mfma_f32_16x16x32_bf16(am, bh_, acc[nt], 0, 0, 0); \
        acc[nt] = __builtin_amdgcn_mfma_f32_16x16x32_bf16(ah, bm_, acc[nt], 0, 0, 0); \
        acc[nt] = __builtin_amdgcn_mfma_f32_16x16x32_bf16(am, bm_, acc[nt], 0, 0, 0); \
        acc[nt] = __builtin_amdgcn_mfma_f32_16x16x32_bf16(ah, bl_, acc[nt], 0, 0, 0); \
        acc[nt] = __builtin_amdgcn_mfma_f32_16x16x32_bf16(al, bh_, acc[nt], 0, 0, 0); \
    } }

__global__ __launch_bounds__(256, 1) void router_main(
    const float* __restrict__ x, const uint4* __restrict__ wq,
    float* __restrict__ out)
{
    // B fragments, 3 planes x double buffer x 4 ntiles x 64 lanes x 8 bf16
    __shared__ __align__(16) unsigned short Bs[3][2][4][512];   // 24 KB
    __shared__ float lg[BT][NEXP + 1];                          // 16.6 KB
    __shared__ float m1s[BT], rss[BT];
    __shared__ float s_ent, s_conf, s_cnt[NEXP];

    const int tid = threadIdx.x;
    const int l   = tid & 63;
    const int wv  = tid >> 6;       // wave id: token tile = 16*wv
    const int qd  = l >> 4;         // k-quad
    const int l8  = l * 8;
    const int t0  = blockIdx.x * BT;

    if (tid == 0) { s_ent = 0.0f; s_conf = 0.0f; }
    if (tid < NEXP) s_cnt[tid] = 0.0f;

    // this thread's A-fragment source: token 16w + (l&15), k-quad qd
    const float4* xq = (const float4*)(x + (size_t)(t0 + 16 * wv + (l & 15)) * DIM);

    f32x4 acc[4];
    #pragma unroll
    for (int nt = 0; nt < 4; ++nt) acc[nt] = (f32x4)(0.0f);

    s16x8 ah, am, al;
    float4 xset0[2], xset1[2];
    uint4  wset0[3], wset1[3];

    // prologue: depth-2 pipeline
    LOADX(0, 0); LOADX(1, 1);
    LOADW(0, 0); LOADW(1, 1);
    STOREW(0, 0);
    __syncthreads();

    for (int c = 0; c < NSTAGE; c += 2) {
        // sub-iter A: chunk c, buf 0, set 0
        CONVX(0);
        if (c + 2 < NSTAGE) { LOADX(0, c + 2); LOADW(0, c + 2); }
        COMPUTE(0);
        STOREW(1, 1);                       // W(c+1) -> buf1 (c <= 62 so c+1 valid)
        __syncthreads();
        // sub-iter B: chunk c+1, buf 1, set 1
        CONVX(1);
        if (c + 3 < NSTAGE) { LOADX(1, c + 3); LOADW(1, c + 3); }
        COMPUTE(1);
        if (c + 2 < NSTAGE) STOREW(0, 0);   // W(c+2) -> buf0
        __syncthreads();
    }

    // C/D layout (verified): col = lane&15 (expert), row = (lane>>4)*4 + reg (token)
    #pragma unroll
    for (int nt = 0; nt < 4; ++nt)
        #pragma unroll
        for (int r = 0; r < 4; ++r)
            lg[16 * wv + 4 * qd + r][16 * nt + (l & 15)] = acc[nt][r];
    __syncthreads();

    // one wave: top-2 + softmax stats per token
    if (tid < BT) {
        const int t = tid;
        float m1 = -INFINITY, m2 = -INFINITY;
        int i1 = 0, i2 = 0;
        for (int e = 0; e < NEXP; ++e) {
            float lv = lg[t][e];
            if (lv > m1)      { m2 = m1; i2 = i1; m1 = lv; i1 = e; }
            else if (lv > m2) { m2 = lv; i2 = e; }
        }
        float ssum = 0.0f, tsum = 0.0f;
        for (int e = 0; e < NEXP; ++e) {
            float d = lg[t][e] - m1;
            float ex = __expf(d);
            ssum += ex;
            tsum += d * ex;
        }
        float rs = 1.0f / ssum;
        float H  = logf(ssum) - tsum * rs;   // H = ln(s) - (sum d e^d)/s
        float e2 = __expf(m2 - m1);
        float rn = 1.0f / (1.0f + e2);
        float w0 = rn, w1v = e2 * rn;
        m1s[t] = m1; rss[t] = rs;

        *(float2*)&out[OFF_W + 2 * (t0 + t)] = make_float2(w0, w1v);
        *(float2*)&out[OFF_I + 2 * (t0 + t)] = make_float2((float)i1, (float)i2);

        atomicAdd(&s_ent,  H);
        atomicAdd(&s_conf, w0);
        atomicAdd(&s_cnt[i1], 1.0f);
        atomicAdd(&s_cnt[i2], 1.0f);
    }
    __syncthreads();

    // cooperative, coalesced probs write: 1024 float4s / 256 threads
    #pragma unroll
    for (int p = 0; p < 4; ++p) {
        int Q  = tid + 256 * p;
        int t  = Q >> 4;
        int qq = Q & 15;
        float m  = m1s[t];
        float rs = rss[t];
        float4 pr;
        pr.x = __expf(lg[t][4 * qq + 0] - m) * rs;
        pr.y = __expf(lg[t][4 * qq + 1] - m) * rs;
        pr.z = __expf(lg[t][4 * qq + 2] - m) * rs;
        pr.w = __expf(lg[t][4 * qq + 3] - m) * rs;
        *(float4*)&out[OFF_P + (size_t)(t0 + t) * NEXP + 4 * qq] = pr;
    }

    // stats: pre-scaled so the atomic sums are exact / final means
    if (tid == 0) {
        atomicAdd(&out[OFF_ENT],  s_ent  * (1.0f / 16384.0f));
        atomicAdd(&out[OFF_CONF], s_conf * (1.0f / 16384.0f));
    }
    if (tid < NEXP)
        atomicAdd(&out[OFF_UTIL + tid], s_cnt[tid] * (1.0f / 32768.0f));
}

extern "C" void kernel_launch(void* const* d_in, const int* in_sizes, int n_in,
                              void* d_out, int out_size, void* d_ws, size_t ws_size,
                              hipStream_t stream) {
    const float* x  = (const float*)d_in[0];
    const float* Wg = (const float*)d_in[1];
    float* out = (float*)d_out;
    (void)in_sizes; (void)n_in; (void)out_size; (void)ws_size;

    router_init<<<dim3(1), dim3(128), 0, stream>>>(out);
    router_wsplit<<<dim3(NSTAGE), dim3(256), 0, stream>>>(Wg, (uint4*)d_ws);
    router_main<<<dim3(NTOK / BT), dim3(256), 0, stream>>>(x, (const uint4*)d_ws, out);
}